// Round 1
// baseline (44.209 us; speedup 1.0000x reference)
//
#include <hip/hip_runtime.h>

#define BB 4096
#define FF 8
#define VV 100000
#define DD 64
#define KK 16

__global__ __launch_bounds__(256) void knn_attn_kernel(
    const int* __restrict__ X,      // [B,F]
    const float* __restrict__ emb,  // [F,V,D]
    const int* __restrict__ adj,    // [F,V,K]
    float* __restrict__ out)        // [B,F,D]
{
    const int gtid = blockIdx.x * blockDim.x + threadIdx.x;
    const int wid  = gtid >> 6;          // one wave per (b,f)
    const int lane = threadIdx.x & 63;   // lane = d
    if (wid >= BB * FF) return;

    const int f = wid & (FF - 1);
    const int x = X[wid];                // wid = b*F + f, X is [B,F] row-major

    const float* __restrict__ embF = emb + (size_t)f * VV * DD;

    // self embedding, coalesced: lane d reads emb[f][x][d]
    const float self = embF[(size_t)x * DD + lane];

    // adj row: lanes 0..15 hold the 16 neighbor ids (lanes 16..63 redundant)
    const int aval = adj[((size_t)f * VV + (size_t)x) * KK + (lane & (KK - 1))];

    // gather 16 neighbor rows into registers: nv[k] = emb[f][adj_k][lane]
    float nv[KK];
#pragma unroll
    for (int k = 0; k < KK; ++k) {
        const int nk = __shfl(aval, k, 64);
        nv[k] = embF[(size_t)nk * DD + lane];
    }

    // scores: dot(self, neighbor_k) over D=64 lanes via butterfly reduce
    float sc[KK];
#pragma unroll
    for (int k = 0; k < KK; ++k) {
        float p = self * nv[k];
#pragma unroll
        for (int m = 32; m >= 1; m >>= 1) p += __shfl_xor(p, m, 64);
        sc[k] = p;   // every lane now holds the full score for neighbor k
    }

    // softmax over K=16 (redundant per lane, register-only)
    float mx = sc[0];
#pragma unroll
    for (int k = 1; k < KK; ++k) mx = fmaxf(mx, sc[k]);
    float ssum = 0.f;
#pragma unroll
    for (int k = 0; k < KK; ++k) { sc[k] = __expf(sc[k] - mx); ssum += sc[k]; }
    const float inv = 1.0f / ssum;

    // weighted sum + residual
    float acc = self;
#pragma unroll
    for (int k = 0; k < KK; ++k) acc = fmaf(sc[k] * inv, nv[k], acc);

    out[(size_t)wid * DD + lane] = acc;
}

extern "C" void kernel_launch(void* const* d_in, const int* in_sizes, int n_in,
                              void* d_out, int out_size, void* d_ws, size_t ws_size,
                              hipStream_t stream) {
    const int*   X   = (const int*)d_in[0];
    const float* emb = (const float*)d_in[1];
    const int*   adj = (const int*)d_in[2];
    float*       out = (float*)d_out;

    const int total_waves   = BB * FF;              // 32768
    const int threads       = 256;                  // 4 waves/block
    const int waves_per_blk = threads / 64;
    const int blocks        = (total_waves + waves_per_blk - 1) / waves_per_blk;

    knn_attn_kernel<<<blocks, threads, 0, stream>>>(X, emb, adj, out);
}

// Round 2
// 28.304 us; speedup vs baseline: 1.5619x; 1.5619x over previous
//
#include <hip/hip_runtime.h>

#define BB 4096
#define FF 8
#define VV 100000
#define DD 64
#define KK 16

__global__ __launch_bounds__(256) void knn_attn_kernel(
    const int* __restrict__ X,      // [B,F]
    const float* __restrict__ emb,  // [F,V,D]
    const int* __restrict__ adj,    // [F,V,K]
    float* __restrict__ out)        // [B,F,D]
{
    const int gtid = blockIdx.x * blockDim.x + threadIdx.x;
    const int wid  = gtid >> 6;          // one wave per (b,f)
    const int lane = threadIdx.x & 63;
    if (wid >= BB * FF) return;

    const int c = lane & 15;             // column group: covers d = 4c..4c+3
    const int r = lane >> 4;             // row group: owns rows r, r+4, r+8, r+12

    const int f = wid & (FF - 1);
    const int x = X[wid];

    const float* __restrict__ embF = emb + (size_t)f * VV * DD;

    // adj row: lanes within each group hold the 16 neighbor ids (id k at c==k)
    const int aval = adj[((size_t)f * VV + (size_t)x) * KK + c];

    // self embedding as float4 (same 16 addresses in all 4 row-groups -> broadcast)
    const float4 self4 = *(const float4*)(embF + (size_t)x * DD + 4 * c);

    // neighbor ids for this row-group: k = r + 4j
    int nk[4];
#pragma unroll
    for (int j = 0; j < 4; ++j) nk[j] = __shfl(aval, r + 4 * j, 64);

    // gather 16 neighbor rows with 4 dwordx4 loads (1 KB each, fully coalesced)
    float4 nv4[4];
#pragma unroll
    for (int j = 0; j < 4; ++j)
        nv4[j] = *(const float4*)(embF + (size_t)nk[j] * DD + 4 * c);

    // scores: dot(self, row r+4j) -- partial dot per lane, reduce over the
    // 16 lanes of the row-group (masks 1,2,4,8 stay inside the group)
    float sc[4];
#pragma unroll
    for (int j = 0; j < 4; ++j) {
        float p = self4.x * nv4[j].x + self4.y * nv4[j].y +
                  self4.z * nv4[j].z + self4.w * nv4[j].w;
#pragma unroll
        for (int m = 1; m <= 8; m <<= 1) p += __shfl_xor(p, m, 64);
        sc[j] = p;                       // score of row r+4j, uniform in group r
    }

    // softmax over all 16: local max/sum + cross-group exchange (masks 16,32)
    float mx = fmaxf(fmaxf(sc[0], sc[1]), fmaxf(sc[2], sc[3]));
    mx = fmaxf(mx, __shfl_xor(mx, 16, 64));
    mx = fmaxf(mx, __shfl_xor(mx, 32, 64));

    float ssum = 0.f;
#pragma unroll
    for (int j = 0; j < 4; ++j) { sc[j] = __expf(sc[j] - mx); ssum += sc[j]; }
    ssum += __shfl_xor(ssum, 16, 64);
    ssum += __shfl_xor(ssum, 32, 64);
    const float inv = 1.0f / ssum;

    // weighted sum of this group's 4 rows
    float ax = 0.f, ay = 0.f, az = 0.f, aw = 0.f;
#pragma unroll
    for (int j = 0; j < 4; ++j) {
        const float w = sc[j] * inv;
        ax = fmaf(w, nv4[j].x, ax);
        ay = fmaf(w, nv4[j].y, ay);
        az = fmaf(w, nv4[j].z, az);
        aw = fmaf(w, nv4[j].w, aw);
    }

    // reduce partial output across the 4 row-groups, then add residual
#pragma unroll
    for (int m = 16; m <= 32; m <<= 1) {
        ax += __shfl_xor(ax, m, 64);
        ay += __shfl_xor(ay, m, 64);
        az += __shfl_xor(az, m, 64);
        aw += __shfl_xor(aw, m, 64);
    }

    if (r == 0) {
        float4 o;
        o.x = ax + self4.x;
        o.y = ay + self4.y;
        o.z = az + self4.z;
        o.w = aw + self4.w;
        *(float4*)(out + (size_t)wid * DD + 4 * c) = o;
    }
}

extern "C" void kernel_launch(void* const* d_in, const int* in_sizes, int n_in,
                              void* d_out, int out_size, void* d_ws, size_t ws_size,
                              hipStream_t stream) {
    const int*   X   = (const int*)d_in[0];
    const float* emb = (const float*)d_in[1];
    const int*   adj = (const int*)d_in[2];
    float*       out = (float*)d_out;

    const int total_waves   = BB * FF;              // 32768
    const int threads       = 256;                  // 4 waves/block
    const int waves_per_blk = threads / 64;
    const int blocks        = (total_waves + waves_per_blk - 1) / waves_per_blk;

    knn_attn_kernel<<<blocks, threads, 0, stream>>>(X, emb, adj, out);
}

// Round 3
// 25.893 us; speedup vs baseline: 1.7073x; 1.0931x over previous
//
#include <hip/hip_runtime.h>

#define BB 4096
#define FF 8
#define VV 100000
#define DD 64
#define KK 16

typedef float floatx4 __attribute__((ext_vector_type(4)));

__global__ __launch_bounds__(256) void knn_attn_kernel(
    const int* __restrict__ X,      // [B,F]
    const float* __restrict__ emb,  // [F,V,D]
    const int* __restrict__ adj,    // [F,V,K]
    float* __restrict__ out)        // [B,F,D]
{
    // XCD-aware swizzle: 8192 blocks, HW round-robins blockIdx%8 across the
    // 8 XCDs. Remap so XCD x gets logical blocks [x*1024, (x+1)*1024) and use
    // FIELD-MAJOR wave ids -> each XCD processes exactly ONE field's 25.6 MB
    // table; its 4 MB L2 caches ~16% of it instead of ~2% of eight tables.
    const int nchunk = gridDim.x >> 3;            // 1024
    const int lb     = (blockIdx.x & 7) * nchunk + (blockIdx.x >> 3);
    const int fm_wid = lb * 4 + (int)(threadIdx.x >> 6);   // field-major wave id
    const int lane   = threadIdx.x & 63;

    const int f = fm_wid >> 12;                   // fm_wid / 4096
    const int b = fm_wid & 4095;
    const int wid = b * FF + f;                   // row index into X / out

    const int c = lane & 15;                      // column group: d = 4c..4c+3
    const int r = lane >> 4;                      // row group: rows r+4j

    const int x = X[wid];

    const float* __restrict__ embF = emb + (size_t)f * VV * DD;

    // adj row: 16 neighbor ids, id k held at lanes with c==k
    const int aval = adj[((size_t)f * VV + (size_t)x) * KK + c];

    // self embedding as float4 (same 16 addresses in all 4 row-groups)
    const float4 self4 = *(const float4*)(embF + (size_t)x * DD + 4 * c);

    // neighbor ids for this row-group: k = r + 4j
    int nk[4];
#pragma unroll
    for (int j = 0; j < 4; ++j) nk[j] = __shfl(aval, r + 4 * j, 64);

    // gather 16 neighbor rows with 4 dwordx4 loads (4 x 256B segments each)
    float4 nv4[4];
#pragma unroll
    for (int j = 0; j < 4; ++j)
        nv4[j] = *(const float4*)(embF + (size_t)nk[j] * DD + 4 * c);

    // scores: partial dot per lane, butterfly over the 16 lanes of the group
    float sc[4];
#pragma unroll
    for (int j = 0; j < 4; ++j) {
        float p = self4.x * nv4[j].x + self4.y * nv4[j].y +
                  self4.z * nv4[j].z + self4.w * nv4[j].w;
#pragma unroll
        for (int m = 1; m <= 8; m <<= 1) p += __shfl_xor(p, m, 64);
        sc[j] = p;
    }

    // softmax over all 16: local max/sum + cross-group exchange
    float mx = fmaxf(fmaxf(sc[0], sc[1]), fmaxf(sc[2], sc[3]));
    mx = fmaxf(mx, __shfl_xor(mx, 16, 64));
    mx = fmaxf(mx, __shfl_xor(mx, 32, 64));

    float ssum = 0.f;
#pragma unroll
    for (int j = 0; j < 4; ++j) { sc[j] = __expf(sc[j] - mx); ssum += sc[j]; }
    ssum += __shfl_xor(ssum, 16, 64);
    ssum += __shfl_xor(ssum, 32, 64);
    const float inv = 1.0f / ssum;

    // weighted sum of this group's 4 rows
    float ax = 0.f, ay = 0.f, az = 0.f, aw = 0.f;
#pragma unroll
    for (int j = 0; j < 4; ++j) {
        const float w = sc[j] * inv;
        ax = fmaf(w, nv4[j].x, ax);
        ay = fmaf(w, nv4[j].y, ay);
        az = fmaf(w, nv4[j].z, az);
        aw = fmaf(w, nv4[j].w, aw);
    }

    // reduce partials across the 4 row-groups, add residual, store (group 0)
#pragma unroll
    for (int m = 16; m <= 32; m <<= 1) {
        ax += __shfl_xor(ax, m, 64);
        ay += __shfl_xor(ay, m, 64);
        az += __shfl_xor(az, m, 64);
        aw += __shfl_xor(aw, m, 64);
    }

    if (r == 0) {
        floatx4 o = { ax + self4.x, ay + self4.y, az + self4.z, aw + self4.w };
        __builtin_nontemporal_store(
            o, (floatx4*)(out + (size_t)wid * DD + 4 * c));
    }
}

extern "C" void kernel_launch(void* const* d_in, const int* in_sizes, int n_in,
                              void* d_out, int out_size, void* d_ws, size_t ws_size,
                              hipStream_t stream) {
    const int*   X   = (const int*)d_in[0];
    const float* emb = (const float*)d_in[1];
    const int*   adj = (const int*)d_in[2];
    float*       out = (float*)d_out;

    const int total_waves   = BB * FF;              // 32768
    const int threads       = 256;                  // 4 waves/block
    const int waves_per_blk = threads / 64;
    const int blocks        = (total_waves + waves_per_blk - 1) / waves_per_blk;

    knn_attn_kernel<<<blocks, threads, 0, stream>>>(X, emb, adj, out);
}

// Round 4
// 25.666 us; speedup vs baseline: 1.7225x; 1.0089x over previous
//
#include <hip/hip_runtime.h>

#define BB 4096
#define FF 8
#define VV 100000
#define DD 64
#define KK 16
#define PAIRS 2

typedef float floatx4 __attribute__((ext_vector_type(4)));

__global__ __launch_bounds__(256) void knn_attn_kernel(
    const int* __restrict__ X,      // [B,F]
    const float* __restrict__ emb,  // [F,V,D]
    const int* __restrict__ adj,    // [F,V,K]
    float* __restrict__ out)        // [B,F,D]
{
    // XCD-aware swizzle + field-major: 4096 blocks, XCD x owns logical blocks
    // [x*512,(x+1)*512) -> exactly one field per XCD (L2 caches one table).
    // Each wave handles TWO consecutive batches of that field, loads issued
    // up-front for both -> 2x outstanding VMEM per wave (latency hiding).
    const int nchunk = gridDim.x >> 3;            // 512
    const int lb     = (blockIdx.x & 7) * nchunk + (blockIdx.x >> 3);
    const int fm     = lb * 4 + (int)(threadIdx.x >> 6);   // [0, 16384)
    const int lane   = threadIdx.x & 63;

    const int c = lane & 15;                      // column group: d = 4c..4c+3
    const int r = lane >> 4;                      // row group

    const int f  = fm >> 11;                      // 2048 waves per field
    const int b0 = (fm & 2047) * PAIRS;

    const float* __restrict__ embF = emb + (size_t)f * VV * DD;
    const int*   __restrict__ adjF = adj + (size_t)f * VV * KK;

    int x[PAIRS];
#pragma unroll
    for (int p = 0; p < PAIRS; ++p) x[p] = X[(b0 + p) * FF + f];

    int    aval[PAIRS];
    float4 self4[PAIRS];
#pragma unroll
    for (int p = 0; p < PAIRS; ++p) {
        aval[p]  = adjF[(size_t)x[p] * KK + c];
        self4[p] = *(const float4*)(embF + (size_t)x[p] * DD + 4 * c);
    }

    // gather both pairs' 16 neighbor rows (8 dwordx4 loads in flight)
    float4 nv[PAIRS][4];
#pragma unroll
    for (int p = 0; p < PAIRS; ++p) {
#pragma unroll
        for (int j = 0; j < 4; ++j) {
            const int nk = __shfl(aval[p], r + 4 * j, 64);
            nv[p][j] = *(const float4*)(embF + (size_t)nk * DD + 4 * c);
        }
    }

#pragma unroll
    for (int p = 0; p < PAIRS; ++p) {
        // scores: partial dot per lane, butterfly over the 16-lane group
        float sc[4];
#pragma unroll
        for (int j = 0; j < 4; ++j) {
            float q = self4[p].x * nv[p][j].x + self4[p].y * nv[p][j].y +
                      self4[p].z * nv[p][j].z + self4[p].w * nv[p][j].w;
#pragma unroll
            for (int m = 1; m <= 8; m <<= 1) q += __shfl_xor(q, m, 64);
            sc[j] = q;
        }

        // softmax over all 16: local max/sum + cross-group exchange
        float mx = fmaxf(fmaxf(sc[0], sc[1]), fmaxf(sc[2], sc[3]));
        mx = fmaxf(mx, __shfl_xor(mx, 16, 64));
        mx = fmaxf(mx, __shfl_xor(mx, 32, 64));

        float ssum = 0.f;
#pragma unroll
        for (int j = 0; j < 4; ++j) { sc[j] = __expf(sc[j] - mx); ssum += sc[j]; }
        ssum += __shfl_xor(ssum, 16, 64);
        ssum += __shfl_xor(ssum, 32, 64);
        const float inv = 1.0f / ssum;

        // weighted sum of this group's 4 rows
        float ax = 0.f, ay = 0.f, az = 0.f, aw = 0.f;
#pragma unroll
        for (int j = 0; j < 4; ++j) {
            const float w = sc[j] * inv;
            ax = fmaf(w, nv[p][j].x, ax);
            ay = fmaf(w, nv[p][j].y, ay);
            az = fmaf(w, nv[p][j].z, az);
            aw = fmaf(w, nv[p][j].w, aw);
        }

        // reduce partials across the 4 row-groups, add residual, store
#pragma unroll
        for (int m = 16; m <= 32; m <<= 1) {
            ax += __shfl_xor(ax, m, 64);
            ay += __shfl_xor(ay, m, 64);
            az += __shfl_xor(az, m, 64);
            aw += __shfl_xor(aw, m, 64);
        }

        if (r == 0) {
            floatx4 o = { ax + self4[p].x, ay + self4[p].y,
                          az + self4[p].z, aw + self4[p].w };
            __builtin_nontemporal_store(
                o, (floatx4*)(out + ((size_t)(b0 + p) * FF + f) * DD + 4 * c));
        }
    }
}

extern "C" void kernel_launch(void* const* d_in, const int* in_sizes, int n_in,
                              void* d_out, int out_size, void* d_ws, size_t ws_size,
                              hipStream_t stream) {
    const int*   X   = (const int*)d_in[0];
    const float* emb = (const float*)d_in[1];
    const int*   adj = (const int*)d_in[2];
    float*       out = (float*)d_out;

    const int total_waves   = BB * FF / PAIRS;      // 16384
    const int threads       = 256;                  // 4 waves/block
    const int waves_per_blk = threads / 64;
    const int blocks        = total_waves / waves_per_blk;  // 4096, %8==0

    knn_attn_kernel<<<blocks, threads, 0, stream>>>(X, emb, adj, out);
}